// Round 7
// baseline (2180.661 us; speedup 1.0000x reference)
//
#include <hip/hip_runtime.h>
#include <hip/hip_bf16.h>

// Problem constants: B=2, C=256, H=100, W=152, K=1024 rois, OUT=7, co5=42
#define BB   2
#define CC   256
#define HH   100
#define WW   152
#define CO5  42

// LDS staging geometry: rows 0..48 = data, row 49 = shared zero/pad row.
#define XROWS 50
#define ZROW  49

typedef short short8 __attribute__((ext_vector_type(8)));   // 8 bf16 (4 VGPRs)
typedef float f32x4 __attribute__((ext_vector_type(4)));    // MFMA accumulator

typedef unsigned int uint_t;
typedef unsigned short ushort_t;

__device__ __forceinline__ uint_t bf16_rne(float x) {
    uint_t u = __float_as_uint(x);
    return (u + 0x7fffu + ((u >> 16) & 1u)) >> 16;
}
__device__ __forceinline__ void split_bf16(float x, uint_t& h, uint_t& l) {
    h = bf16_rne(x);
    float hf = __uint_as_float(h << 16);
    l = bf16_rne(x - hf);     // x - hf exact in fp32
}

// ---------------------------------------------------------------------------
// Kernel 1: NCHW -> NHWC feature transpose (for coalesced roi-align gathers)
// ---------------------------------------------------------------------------
__global__ void ftrans_kernel(const float* __restrict__ f, float* __restrict__ ft) {
    __shared__ float tile[32][33];
    const int x0 = blockIdx.x * 32;
    const int c0 = blockIdx.y * 32;
    const int by = blockIdx.z;            // b*H + y
    const int b = by / HH, y = by % HH;
    const int tx = threadIdx.x, ty = threadIdx.y;
    #pragma unroll
    for (int j = 0; j < 4; ++j) {
        int c = c0 + ty + j * 8;
        int x = x0 + tx;
        if (x < WW)
            tile[ty + j * 8][tx] = f[(((size_t)b * CC + c) * HH + y) * WW + x];
    }
    __syncthreads();
    #pragma unroll
    for (int j = 0; j < 4; ++j) {
        int x = x0 + ty + j * 8;
        int c = c0 + tx;
        if (x < WW)
            ft[(((size_t)b * HH + y) * WW + x) * CC + c] = tile[tx][ty + j * 8];
    }
}

// ---------------------------------------------------------------------------
// Kernel 2: weight prep.  W[co][ci][3][3] fp32 -> wh/wl[tap][co][ci] bf16 hi/lo.
// ---------------------------------------------------------------------------
__global__ void wprep_kernel(const float* __restrict__ W,
                             ushort_t* __restrict__ wh, ushort_t* __restrict__ wl) {
    int idx = blockIdx.x * 256 + threadIdx.x;     // 9*256*256 = 589,824 exact
    int tap = idx >> 16;
    int rem = idx & 0xffff;
    int co = rem >> 8, ci = rem & 255;
    float v = W[(size_t)((co << 8) + ci) * 9 + tap];
    uint_t h, l; split_bf16(v, h, l);
    wh[idx] = (ushort_t)h;
    wl[idx] = (ushort_t)l;
}

// Final layer: pad co 42 -> 48.  wh/wl[tap][48][256].
__global__ void wprep5_kernel(const float* __restrict__ W,
                              ushort_t* __restrict__ wh, ushort_t* __restrict__ wl) {
    int idx = blockIdx.x * 256 + threadIdx.x;     // 9*48*256 = 110,592 exact
    int tap = idx / 12288;
    int rem = idx % 12288;
    int co = rem >> 8, ci = rem & 255;
    float v = (co < CO5) ? W[(size_t)((co << 8) + ci) * 9 + tap] : 0.0f;
    uint_t h, l; split_bf16(v, h, l);
    wh[idx] = (ushort_t)h;
    wl[idx] = (ushort_t)l;
}

// ---------------------------------------------------------------------------
// LDS staging from a [49][256] fp32 global tile -> hi/lo bf16 [50][256],
// row 49 zeroed.  XOR swizzle on the full within-row byte offset:
//   addr = row*512 + (byteoff ^ ((row&7)<<4))
// ---------------------------------------------------------------------------
__device__ __forceinline__ void stage_roi(const float* __restrict__ src,
                                          ushort_t* Xh, ushort_t* Xl, int t) {
    const float2* s2 = (const float2*)src;
    const int half = t >> 7;          // 0/1: even/odd rows
    const int cw = t & 127;           // ci pair index
    #pragma unroll
    for (int i = 0; i < 25; ++i) {
        int row = i * 2 + half;       // covers 0..49 exactly
        int addr = row * 512 + ((cw * 4) ^ ((row & 7) << 4));
        uint_t ph = 0u, pl = 0u;
        if (row < 49) {
            float2 v = s2[row * 128 + cw];
            uint_t h0, l0, h1, l1;
            split_bf16(v.x, h0, l0);
            split_bf16(v.y, h1, l1);
            ph = h0 | (h1 << 16);
            pl = l0 | (l1 << 16);
        }
        *(uint_t*)((char*)Xh + addr) = ph;
        *(uint_t*)((char*)Xl + addr) = pl;
    }
}

// ---------------------------------------------------------------------------
// Fused roi-align staging: bilinear-sample NHWC features straight into the
// swizzled LDS hi/lo buffers (skips the global roi-align round trip).
// Thread t: rows of parity (t>>7), ci pair cw = t&127 -> identical LDS
// addressing to stage_roi.  (Reference valid-mask provably always true.)
// ---------------------------------------------------------------------------
__device__ __forceinline__ void stage_roi_align(const float* __restrict__ ft,
                                                const float* __restrict__ rois,
                                                ushort_t* Xh, ushort_t* Xl,
                                                int roi, int t) {
    const float bf = rois[roi * 5 + 0];
    const float x1 = rois[roi * 5 + 1];
    const float y1 = rois[roi * 5 + 2];
    const float x2 = rois[roi * 5 + 3];
    const float y2 = rois[roi * 5 + 4];
    const int b = (int)bf;
    const float rw = fmaxf(x2 - x1, 1.0f);
    const float rh = fmaxf(y2 - y1, 1.0f);
    const float stepy = rh / 7.0f;
    const float stepx = rw / 7.0f;

    const int half = t >> 7;
    const int cw = t & 127;
    const float* base = ft + (size_t)b * HH * WW * CC + cw * 2;

    #pragma unroll
    for (int i = 0; i < 25; ++i) {
        int row = i * 2 + half;       // 0..49
        int addr = row * 512 + ((cw * 4) ^ ((row & 7) << 4));
        uint_t ph = 0u, pl = 0u;
        if (row < 49) {
            int py = row / 7, px = row - (row / 7) * 7;
            float sx = 0.0f, sy_ = 0.0f;    // accum for ci pair (.x, .y)
            #pragma unroll
            for (int j = 0; j < 4; ++j) {
                const int syi = py * 2 + (j >> 1);
                const int sxi = px * 2 + (j & 1);
                float gy = y1 + ((float)syi + 0.5f) * 0.5f * stepy;
                float gx = x1 + ((float)sxi + 0.5f) * 0.5f * stepx;
                float yc = fminf(fmaxf(gy, 0.0f), (float)(HH - 1));
                float xc = fminf(fmaxf(gx, 0.0f), (float)(WW - 1));
                float y0f = fminf(floorf(yc), (float)(HH - 2));
                float x0f = fminf(floorf(xc), (float)(WW - 2));
                float wy = yc - y0f;
                float wx = xc - x0f;
                int y0 = (int)y0f, x0 = (int)x0f;
                const float* p = base + ((size_t)y0 * WW + x0) * CC;
                float2 v00 = *(const float2*)(p);
                float2 v01 = *(const float2*)(p + CC);
                float2 v10 = *(const float2*)(p + (size_t)WW * CC);
                float2 v11 = *(const float2*)(p + (size_t)WW * CC + CC);
                float w00 = (1.0f - wy) * (1.0f - wx);
                float w01 = (1.0f - wy) * wx;
                float w10 = wy * (1.0f - wx);
                float w11 = wy * wx;
                sx  += w00 * v00.x + w01 * v01.x + w10 * v10.x + w11 * v11.x;
                sy_ += w00 * v00.y + w01 * v01.y + w10 * v10.y + w11 * v11.y;
            }
            uint_t h0, l0, h1, l1;
            split_bf16(0.25f * sx, h0, l0);
            split_bf16(0.25f * sy_, h1, l1);
            ph = h0 | (h1 << 16);
            pl = l0 | (l1 << 16);
        }
        *(uint_t*)((char*)Xh + addr) = ph;
        *(uint_t*)((char*)Xl + addr) = pl;
    }
}

// ---------------------------------------------------------------------------
// Shared MFMA conv core (256->256): 9 per-tap GEMMs, split-bf16, 3 products.
// 4 waves x 64 cols; A rows remapped per tap via LDS row index (ZROW=zeros).
// ---------------------------------------------------------------------------
__device__ __forceinline__ void conv_core_256(
        const char* Xhc, const char* Xlc,
        const ushort_t* __restrict__ wh, const ushort_t* __restrict__ wl,
        const float* __restrict__ bias, float* __restrict__ outp,
        int relu, int t) {
    const int wv = t >> 6, l = t & 63;
    const int lr = l & 15;               // A-row-in-tile / B-col / D-col
    const int lk = l >> 4;               // k-group
    const int n0 = wv * 64;
    const int lk16 = lk * 16;

    f32x4 acc[4][4];
    #pragma unroll
    for (int a = 0; a < 4; ++a)
        #pragma unroll
        for (int b = 0; b < 4; ++b) acc[a][b] = {0.f, 0.f, 0.f, 0.f};

    const int bvoff = ((n0 + lr) * 256 + lk * 8) * 2;   // byte off within tap

    for (int tap = 0; tap < 9; ++tap) {
        const int ky = tap / 3 - 1, kx = tap % 3 - 1;
        int arow[4], amask[4];
        #pragma unroll
        for (int mt = 0; mt < 4; ++mt) {
            int m = mt * 16 + lr;
            int py = m / 7, px = m - (m / 7) * 7;
            int y = py + ky, x = px + kx;
            bool ok = (m < 49) && (y >= 0) && (y < 7) && (x >= 0) && (x < 7);
            int srow = ok ? (y * 7 + x) : ZROW;        // ZROW = zero row
            arow[mt]  = srow * 512;
            amask[mt] = (srow & 7) << 4;
        }
        const char* wht = (const char*)wh + tap * 131072;
        const char* wlt = (const char*)wl + tap * 131072;
        #pragma unroll
        for (int kc = 0; kc < 8; ++kc) {
            short8 ah[4], al[4];
            #pragma unroll
            for (int mt = 0; mt < 4; ++mt) {
                const int off = arow[mt] + ((lk16 + kc * 64) ^ amask[mt]);
                ah[mt] = *(const short8*)(Xhc + off);
                al[mt] = *(const short8*)(Xlc + off);
            }
            #pragma unroll
            for (int nt = 0; nt < 4; ++nt) {
                const int woff = bvoff + nt * 8192 + kc * 64;
                short8 bh = *(const short8*)(wht + woff);
                short8 bl = *(const short8*)(wlt + woff);
                #pragma unroll
                for (int mt = 0; mt < 4; ++mt)
                    acc[mt][nt] = __builtin_amdgcn_mfma_f32_16x16x32_bf16(ah[mt], bh, acc[mt][nt], 0, 0, 0);
                #pragma unroll
                for (int mt = 0; mt < 4; ++mt)
                    acc[mt][nt] = __builtin_amdgcn_mfma_f32_16x16x32_bf16(al[mt], bh, acc[mt][nt], 0, 0, 0);
                #pragma unroll
                for (int mt = 0; mt < 4; ++mt)
                    acc[mt][nt] = __builtin_amdgcn_mfma_f32_16x16x32_bf16(ah[mt], bl, acc[mt][nt], 0, 0, 0);
            }
        }
    }

    #pragma unroll
    for (int nt = 0; nt < 4; ++nt) {
        const int co = n0 + nt * 16 + lr;
        const float bv = bias[co];
        #pragma unroll
        for (int mt = 0; mt < 4; ++mt) {
            #pragma unroll
            for (int r = 0; r < 4; ++r) {
                int m = mt * 16 + lk * 4 + r;         // D row = (l>>4)*4+reg
                if (m < 49) {
                    float v = acc[mt][nt][r] + bv;
                    if (relu) v = fmaxf(v, 0.0f);
                    outp[m * 256 + co] = v;           // D col = l&15 -> co
                }
            }
        }
    }
}

// ---------------------------------------------------------------------------
// Kernel 3: fused roi-align + conv1 (256->256, relu)
// ---------------------------------------------------------------------------
__global__ __launch_bounds__(256, 3) void conv1_fused_kernel(
        const float* __restrict__ ft, const float* __restrict__ rois,
        float* __restrict__ out,
        const ushort_t* __restrict__ wh, const ushort_t* __restrict__ wl,
        const float* __restrict__ bias) {
    __shared__ ushort_t X[2][XROWS * 256];   // 51,200 B -> 3 blocks/CU
    const int roi = blockIdx.x, t = threadIdx.x;
    stage_roi_align(ft, rois, X[0], X[1], roi, t);
    __syncthreads();
    conv_core_256((const char*)X[0], (const char*)X[1], wh, wl, bias,
                  out + (size_t)roi * 49 * CC, 1, t);
}

// ---------------------------------------------------------------------------
// Kernel 4: mid conv (256->256, relu), in-place safe.
// ---------------------------------------------------------------------------
__global__ __launch_bounds__(256, 3) void conv_mfma_kernel(
        const float* __restrict__ in, float* __restrict__ out,
        const ushort_t* __restrict__ wh, const ushort_t* __restrict__ wl,
        const float* __restrict__ bias) {
    __shared__ ushort_t X[2][XROWS * 256];
    const int roi = blockIdx.x, t = threadIdx.x;
    stage_roi(in + (size_t)roi * 49 * CC, X[0], X[1], t);
    __syncthreads();
    conv_core_256((const char*)X[0], (const char*)X[1], wh, wl, bias,
                  out + (size_t)roi * 49 * CC, 1, t);
}

// ---------------------------------------------------------------------------
// Kernel 5: final conv 256->42 (padded 48).  4 waves split K by tap groups
// {3,2,2,2}; partials reduced through LDS (X reused).  Output (K,42,7,7).
// ---------------------------------------------------------------------------
__global__ __launch_bounds__(256, 3) void conv5_mfma_kernel(
        const float* __restrict__ in, float* __restrict__ out,
        const ushort_t* __restrict__ wh, const ushort_t* __restrict__ wl,
        const float* __restrict__ b5) {
    __shared__ ushort_t X[2][XROWS * 256];
    const int roi = blockIdx.x, t = threadIdx.x;
    stage_roi(in + (size_t)roi * 49 * CC, X[0], X[1], t);
    __syncthreads();

    const int wv = t >> 6, l = t & 63;
    const int lr = l & 15, lk = l >> 4;
    const int lk16 = lk * 16;

    f32x4 acc[4][3];
    #pragma unroll
    for (int a = 0; a < 4; ++a)
        #pragma unroll
        for (int b = 0; b < 3; ++b) acc[a][b] = {0.f, 0.f, 0.f, 0.f};

    const int bvoff = (lr * 256 + lk * 8) * 2;
    const char* Xhc = (const char*)X[0];
    const char* Xlc = (const char*)X[1];
    const int t0 = (wv == 0) ? 0 : (2 * wv + 1);
    const int t1 = 2 * wv + 3;

    for (int tap = t0; tap < t1; ++tap) {
        const int ky = tap / 3 - 1, kx = tap % 3 - 1;
        int arow[4], amask[4];
        #pragma unroll
        for (int mt = 0; mt < 4; ++mt) {
            int m = mt * 16 + lr;
            int py = m / 7, px = m - (m / 7) * 7;
            int y = py + ky, x = px + kx;
            bool ok = (m < 49) && (y >= 0) && (y < 7) && (x >= 0) && (x < 7);
            int srow = ok ? (y * 7 + x) : ZROW;
            arow[mt]  = srow * 512;
            amask[mt] = (srow & 7) << 4;
        }
        const char* wht = (const char*)wh + tap * 24576;   // 48*256*2
        const char* wlt = (const char*)wl + tap * 24576;
        #pragma unroll
        for (int kc = 0; kc < 8; ++kc) {
            short8 ah[4], al[4];
            #pragma unroll
            for (int mt = 0; mt < 4; ++mt) {
                const int off = arow[mt] + ((lk16 + kc * 64) ^ amask[mt]);
                ah[mt] = *(const short8*)(Xhc + off);
                al[mt] = *(const short8*)(Xlc + off);
            }
            #pragma unroll
            for (int nt = 0; nt < 3; ++nt) {
                const int woff = bvoff + nt * 8192 + kc * 64;
                short8 bh = *(const short8*)(wht + woff);
                short8 bl = *(const short8*)(wlt + woff);
                #pragma unroll
                for (int mt = 0; mt < 4; ++mt)
                    acc[mt][nt] = __builtin_amdgcn_mfma_f32_16x16x32_bf16(ah[mt], bh, acc[mt][nt], 0, 0, 0);
                #pragma unroll
                for (int mt = 0; mt < 4; ++mt)
                    acc[mt][nt] = __builtin_amdgcn_mfma_f32_16x16x32_bf16(al[mt], bh, acc[mt][nt], 0, 0, 0);
                #pragma unroll
                for (int mt = 0; mt < 4; ++mt)
                    acc[mt][nt] = __builtin_amdgcn_mfma_f32_16x16x32_bf16(ah[mt], bl, acc[mt][nt], 0, 0, 0);
            }
        }
    }

    __syncthreads();                       // all waves done reading X
    float* P = (float*)X;                  // reuse: [wave][m64][n48] = 48KB
    #pragma unroll
    for (int nt = 0; nt < 3; ++nt)
        #pragma unroll
        for (int mt = 0; mt < 4; ++mt)
            #pragma unroll
            for (int r = 0; r < 4; ++r) {
                int m = mt * 16 + lk * 4 + r;
                P[wv * 3072 + m * 48 + nt * 16 + lr] = acc[mt][nt][r];
            }
    __syncthreads();

    for (int i = t; i < 49 * CO5; i += 256) {     // 2058 outputs
        int n = i / 49, m = i % 49;
        float s = P[m * 48 + n] + P[3072 + m * 48 + n]
                + P[6144 + m * 48 + n] + P[9216 + m * 48 + n] + b5[n];
        out[(size_t)roi * (49 * CO5) + i] = s;    // out[roi][co][py][px]
    }
}

// ---------------------------------------------------------------------------
extern "C" void kernel_launch(void* const* d_in, const int* in_sizes, int n_in,
                              void* d_out, int out_size, void* d_ws, size_t ws_size,
                              hipStream_t stream) {
    const float* features = (const float*)d_in[0];
    const float* rois     = (const float*)d_in[1];
    const float* W1 = (const float*)d_in[2];
    const float* b1 = (const float*)d_in[3];
    const float* W2 = (const float*)d_in[4];
    const float* b2 = (const float*)d_in[5];
    const float* W3 = (const float*)d_in[6];
    const float* b3 = (const float*)d_in[7];
    const float* W4 = (const float*)d_in[8];
    const float* b4 = (const float*)d_in[9];
    const float* W5 = (const float*)d_in[10];
    const float* b5 = (const float*)d_in[11];
    float* out = (float*)d_out;

    const int K = in_sizes[1] / 5;   // 1024 rois

    // workspace layout (bytes)
    char* wsb = (char*)d_ws;
    float* ft   = (float*)wsb;                                // 31,129,600 B
    float* buf0 = (float*)(wsb + 31129600);                   // 51,380,224 B
    char* wb = wsb + 31129600 + 51380224;
    ushort_t* w1h = (ushort_t*)(wb + 0 * 1179648);
    ushort_t* w1l = (ushort_t*)(wb + 1 * 1179648);
    ushort_t* w2h = (ushort_t*)(wb + 2 * 1179648);
    ushort_t* w2l = (ushort_t*)(wb + 3 * 1179648);
    ushort_t* w3h = (ushort_t*)(wb + 4 * 1179648);
    ushort_t* w3l = (ushort_t*)(wb + 5 * 1179648);
    ushort_t* w4h = (ushort_t*)(wb + 6 * 1179648);
    ushort_t* w4l = (ushort_t*)(wb + 7 * 1179648);
    ushort_t* w5h = (ushort_t*)(wb + 8 * 1179648);
    ushort_t* w5l = (ushort_t*)(wb + 8 * 1179648 + 221184);
    // total = 92,389,376 B

    // 1. feature transpose
    {
        dim3 grid((WW + 31) / 32, CC / 32, BB * HH);
        dim3 block(32, 8);
        ftrans_kernel<<<grid, block, 0, stream>>>(features, ft);
    }
    // 2. weight prep (hi/lo bf16, [tap][co][ci])
    wprep_kernel<<<2304, 256, 0, stream>>>(W1, w1h, w1l);
    wprep_kernel<<<2304, 256, 0, stream>>>(W2, w2h, w2l);
    wprep_kernel<<<2304, 256, 0, stream>>>(W3, w3h, w3l);
    wprep_kernel<<<2304, 256, 0, stream>>>(W4, w4h, w4l);
    wprep5_kernel<<<432, 256, 0, stream>>>(W5, w5h, w5l);
    // 3. fused roi-align + conv1 -> buf0
    conv1_fused_kernel<<<K, 256, 0, stream>>>(ft, rois, buf0, w1h, w1l, b1);
    // 4. conv chain on MFMA, in-place on buf0
    conv_mfma_kernel<<<K, 256, 0, stream>>>(buf0, buf0, w2h, w2l, b2);
    conv_mfma_kernel<<<K, 256, 0, stream>>>(buf0, buf0, w3h, w3l, b3);
    conv_mfma_kernel<<<K, 256, 0, stream>>>(buf0, buf0, w4h, w4l, b4);
    // 5. final conv -> out
    conv5_mfma_kernel<<<K, 256, 0, stream>>>(buf0, out, w5h, w5l, b5);
}

// Round 8
// 1336.446 us; speedup vs baseline: 1.6317x; 1.6317x over previous
//
#include <hip/hip_runtime.h>
#include <hip/hip_bf16.h>

// Problem constants: B=2, C=256, H=100, W=152, K=1024 rois, OUT=7, co5=42
#define BB   2
#define CC   256
#define HH   100
#define WW   152
#define CO5  42

// LDS staging geometry: rows 0..48 = data, row 49 = shared zero/pad row.
#define XROWS 50
#define ZROW  49

typedef short short8 __attribute__((ext_vector_type(8)));   // 8 bf16 (4 VGPRs)
typedef float f32x4 __attribute__((ext_vector_type(4)));    // MFMA accumulator

typedef unsigned int uint_t;
typedef unsigned short ushort_t;

__device__ __forceinline__ uint_t bf16_rne(float x) {
    uint_t u = __float_as_uint(x);
    return (u + 0x7fffu + ((u >> 16) & 1u)) >> 16;
}
__device__ __forceinline__ void split_bf16(float x, uint_t& h, uint_t& l) {
    h = bf16_rne(x);
    float hf = __uint_as_float(h << 16);
    l = bf16_rne(x - hf);     // x - hf exact in fp32
}

// ---------------------------------------------------------------------------
// Kernel 1: NCHW -> NHWC feature transpose (for coalesced roi-align gathers)
// ---------------------------------------------------------------------------
__global__ void ftrans_kernel(const float* __restrict__ f, float* __restrict__ ft) {
    __shared__ float tile[32][33];
    const int x0 = blockIdx.x * 32;
    const int c0 = blockIdx.y * 32;
    const int by = blockIdx.z;            // b*H + y
    const int b = by / HH, y = by % HH;
    const int tx = threadIdx.x, ty = threadIdx.y;
    #pragma unroll
    for (int j = 0; j < 4; ++j) {
        int c = c0 + ty + j * 8;
        int x = x0 + tx;
        if (x < WW)
            tile[ty + j * 8][tx] = f[(((size_t)b * CC + c) * HH + y) * WW + x];
    }
    __syncthreads();
    #pragma unroll
    for (int j = 0; j < 4; ++j) {
        int x = x0 + ty + j * 8;
        int c = c0 + tx;
        if (x < WW)
            ft[(((size_t)b * HH + y) * WW + x) * CC + c] = tile[tx][ty + j * 8];
    }
}

// ---------------------------------------------------------------------------
// Kernel 2: weight prep.  W[co][ci][3][3] fp32 -> wh/wl[tap][co][ci] bf16 hi/lo.
// ---------------------------------------------------------------------------
__global__ void wprep_kernel(const float* __restrict__ W,
                             ushort_t* __restrict__ wh, ushort_t* __restrict__ wl) {
    int idx = blockIdx.x * 256 + threadIdx.x;     // 9*256*256 = 589,824 exact
    int tap = idx >> 16;
    int rem = idx & 0xffff;
    int co = rem >> 8, ci = rem & 255;
    float v = W[(size_t)((co << 8) + ci) * 9 + tap];
    uint_t h, l; split_bf16(v, h, l);
    wh[idx] = (ushort_t)h;
    wl[idx] = (ushort_t)l;
}

// Final layer: pad co 42 -> 48.  wh/wl[tap][48][256].
__global__ void wprep5_kernel(const float* __restrict__ W,
                              ushort_t* __restrict__ wh, ushort_t* __restrict__ wl) {
    int idx = blockIdx.x * 256 + threadIdx.x;     // 9*48*256 = 110,592 exact
    int tap = idx / 12288;
    int rem = idx % 12288;
    int co = rem >> 8, ci = rem & 255;
    float v = (co < CO5) ? W[(size_t)((co << 8) + ci) * 9 + tap] : 0.0f;
    uint_t h, l; split_bf16(v, h, l);
    wh[idx] = (ushort_t)h;
    wl[idx] = (ushort_t)l;
}

// ---------------------------------------------------------------------------
// LDS staging from a [49][256] fp32 global tile -> hi/lo bf16 [50][256],
// row 49 zeroed.  XOR swizzle on the full within-row byte offset:
//   addr = row*512 + (byteoff ^ ((row&7)<<4))
// ---------------------------------------------------------------------------
__device__ __forceinline__ void stage_roi(const float* __restrict__ src,
                                          ushort_t* Xh, ushort_t* Xl, int t) {
    const float2* s2 = (const float2*)src;
    const int half = t >> 7;          // 0/1: even/odd rows
    const int cw = t & 127;           // ci pair index
    #pragma unroll
    for (int i = 0; i < 25; ++i) {
        int row = i * 2 + half;       // covers 0..49 exactly
        int addr = row * 512 + ((cw * 4) ^ ((row & 7) << 4));
        uint_t ph = 0u, pl = 0u;
        if (row < 49) {
            float2 v = s2[row * 128 + cw];
            uint_t h0, l0, h1, l1;
            split_bf16(v.x, h0, l0);
            split_bf16(v.y, h1, l1);
            ph = h0 | (h1 << 16);
            pl = l0 | (l1 << 16);
        }
        *(uint_t*)((char*)Xh + addr) = ph;
        *(uint_t*)((char*)Xl + addr) = pl;
    }
}

// ---------------------------------------------------------------------------
// Fused roi-align staging: bilinear-sample NHWC features straight into the
// swizzled LDS hi/lo buffers (skips the global roi-align round trip).
// Thread t: rows of parity (t>>7), ci pair cw = t&127 -> identical LDS
// addressing to stage_roi.  (Reference valid-mask provably always true.)
// ---------------------------------------------------------------------------
__device__ __forceinline__ void stage_roi_align(const float* __restrict__ ft,
                                                const float* __restrict__ rois,
                                                ushort_t* Xh, ushort_t* Xl,
                                                int roi, int t) {
    const float bf = rois[roi * 5 + 0];
    const float x1 = rois[roi * 5 + 1];
    const float y1 = rois[roi * 5 + 2];
    const float x2 = rois[roi * 5 + 3];
    const float y2 = rois[roi * 5 + 4];
    const int b = (int)bf;
    const float rw = fmaxf(x2 - x1, 1.0f);
    const float rh = fmaxf(y2 - y1, 1.0f);
    const float stepy = rh / 7.0f;
    const float stepx = rw / 7.0f;

    const int half = t >> 7;
    const int cw = t & 127;
    const float* base = ft + (size_t)b * HH * WW * CC + cw * 2;

    #pragma unroll
    for (int i = 0; i < 25; ++i) {
        int row = i * 2 + half;       // 0..49
        int addr = row * 512 + ((cw * 4) ^ ((row & 7) << 4));
        uint_t ph = 0u, pl = 0u;
        if (row < 49) {
            int py = row / 7, px = row - (row / 7) * 7;
            float sx = 0.0f, sy_ = 0.0f;    // accum for ci pair (.x, .y)
            #pragma unroll
            for (int j = 0; j < 4; ++j) {
                const int syi = py * 2 + (j >> 1);
                const int sxi = px * 2 + (j & 1);
                float gy = y1 + ((float)syi + 0.5f) * 0.5f * stepy;
                float gx = x1 + ((float)sxi + 0.5f) * 0.5f * stepx;
                float yc = fminf(fmaxf(gy, 0.0f), (float)(HH - 1));
                float xc = fminf(fmaxf(gx, 0.0f), (float)(WW - 1));
                float y0f = fminf(floorf(yc), (float)(HH - 2));
                float x0f = fminf(floorf(xc), (float)(WW - 2));
                float wy = yc - y0f;
                float wx = xc - x0f;
                int y0 = (int)y0f, x0 = (int)x0f;
                const float* p = base + ((size_t)y0 * WW + x0) * CC;
                float2 v00 = *(const float2*)(p);
                float2 v01 = *(const float2*)(p + CC);
                float2 v10 = *(const float2*)(p + (size_t)WW * CC);
                float2 v11 = *(const float2*)(p + (size_t)WW * CC + CC);
                float w00 = (1.0f - wy) * (1.0f - wx);
                float w01 = (1.0f - wy) * wx;
                float w10 = wy * (1.0f - wx);
                float w11 = wy * wx;
                sx  += w00 * v00.x + w01 * v01.x + w10 * v10.x + w11 * v11.x;
                sy_ += w00 * v00.y + w01 * v01.y + w10 * v10.y + w11 * v11.y;
            }
            uint_t h0, l0, h1, l1;
            split_bf16(0.25f * sx, h0, l0);
            split_bf16(0.25f * sy_, h1, l1);
            ph = h0 | (h1 << 16);
            pl = l0 | (l1 << 16);
        }
        *(uint_t*)((char*)Xh + addr) = ph;
        *(uint_t*)((char*)Xl + addr) = pl;
    }
}

// ---------------------------------------------------------------------------
// Shared MFMA conv core (256->256): 9 per-tap GEMMs, split-bf16, 3 products.
// 4 waves x 64 cols; A rows remapped per tap via LDS row index (ZROW=zeros).
// ---------------------------------------------------------------------------
__device__ __forceinline__ void conv_core_256(
        const char* Xhc, const char* Xlc,
        const ushort_t* __restrict__ wh, const ushort_t* __restrict__ wl,
        const float* __restrict__ bias, float* __restrict__ outp,
        int relu, int t) {
    const int wv = t >> 6, l = t & 63;
    const int lr = l & 15;               // A-row-in-tile / B-col / D-col
    const int lk = l >> 4;               // k-group
    const int n0 = wv * 64;
    const int lk16 = lk * 16;

    f32x4 acc[4][4];
    #pragma unroll
    for (int a = 0; a < 4; ++a)
        #pragma unroll
        for (int b = 0; b < 4; ++b) acc[a][b] = {0.f, 0.f, 0.f, 0.f};

    const int bvoff = ((n0 + lr) * 256 + lk * 8) * 2;   // byte off within tap

    for (int tap = 0; tap < 9; ++tap) {
        const int ky = tap / 3 - 1, kx = tap % 3 - 1;
        int arow[4], amask[4];
        #pragma unroll
        for (int mt = 0; mt < 4; ++mt) {
            int m = mt * 16 + lr;
            int py = m / 7, px = m - (m / 7) * 7;
            int y = py + ky, x = px + kx;
            bool ok = (m < 49) && (y >= 0) && (y < 7) && (x >= 0) && (x < 7);
            int srow = ok ? (y * 7 + x) : ZROW;        // ZROW = zero row
            arow[mt]  = srow * 512;
            amask[mt] = (srow & 7) << 4;
        }
        const char* wht = (const char*)wh + tap * 131072;
        const char* wlt = (const char*)wl + tap * 131072;
        #pragma unroll
        for (int kc = 0; kc < 8; ++kc) {
            short8 ah[4], al[4];
            #pragma unroll
            for (int mt = 0; mt < 4; ++mt) {
                const int off = arow[mt] + ((lk16 + kc * 64) ^ amask[mt]);
                ah[mt] = *(const short8*)(Xhc + off);
                al[mt] = *(const short8*)(Xlc + off);
            }
            #pragma unroll
            for (int nt = 0; nt < 4; ++nt) {
                const int woff = bvoff + nt * 8192 + kc * 64;
                short8 bh = *(const short8*)(wht + woff);
                short8 bl = *(const short8*)(wlt + woff);
                #pragma unroll
                for (int mt = 0; mt < 4; ++mt)
                    acc[mt][nt] = __builtin_amdgcn_mfma_f32_16x16x32_bf16(ah[mt], bh, acc[mt][nt], 0, 0, 0);
                #pragma unroll
                for (int mt = 0; mt < 4; ++mt)
                    acc[mt][nt] = __builtin_amdgcn_mfma_f32_16x16x32_bf16(al[mt], bh, acc[mt][nt], 0, 0, 0);
                #pragma unroll
                for (int mt = 0; mt < 4; ++mt)
                    acc[mt][nt] = __builtin_amdgcn_mfma_f32_16x16x32_bf16(ah[mt], bl, acc[mt][nt], 0, 0, 0);
            }
        }
    }

    #pragma unroll
    for (int nt = 0; nt < 4; ++nt) {
        const int co = n0 + nt * 16 + lr;
        const float bv = bias[co];
        #pragma unroll
        for (int mt = 0; mt < 4; ++mt) {
            #pragma unroll
            for (int r = 0; r < 4; ++r) {
                int m = mt * 16 + lk * 4 + r;         // D row = (l>>4)*4+reg
                if (m < 49) {
                    float v = acc[mt][nt][r] + bv;
                    if (relu) v = fmaxf(v, 0.0f);
                    outp[m * 256 + co] = v;           // D col = l&15 -> co
                }
            }
        }
    }
}

// ---------------------------------------------------------------------------
// Kernel 3: fused roi-align + conv1 (256->256, relu)
// NOTE: __launch_bounds__(256, 2) — NOT 3.  Round-7 lesson: min-waves=3 made
// the allocator emit an 84-VGPR spill body (WRITE_SIZE 50->128 MB, FETCH
// 44->400+ MB, 1.6x total regression).  LDS=51,200B alone gives 3 blocks/CU.
// ---------------------------------------------------------------------------
__global__ __launch_bounds__(256, 2) void conv1_fused_kernel(
        const float* __restrict__ ft, const float* __restrict__ rois,
        float* __restrict__ out,
        const ushort_t* __restrict__ wh, const ushort_t* __restrict__ wl,
        const float* __restrict__ bias) {
    __shared__ ushort_t X[2][XROWS * 256];   // 51,200 B -> 3 blocks/CU by LDS
    const int roi = blockIdx.x, t = threadIdx.x;
    stage_roi_align(ft, rois, X[0], X[1], roi, t);
    __syncthreads();
    conv_core_256((const char*)X[0], (const char*)X[1], wh, wl, bias,
                  out + (size_t)roi * 49 * CC, 1, t);
}

// ---------------------------------------------------------------------------
// Kernel 4: mid conv (256->256, relu), in-place safe.
// ---------------------------------------------------------------------------
__global__ __launch_bounds__(256, 2) void conv_mfma_kernel(
        const float* __restrict__ in, float* __restrict__ out,
        const ushort_t* __restrict__ wh, const ushort_t* __restrict__ wl,
        const float* __restrict__ bias) {
    __shared__ ushort_t X[2][XROWS * 256];
    const int roi = blockIdx.x, t = threadIdx.x;
    stage_roi(in + (size_t)roi * 49 * CC, X[0], X[1], t);
    __syncthreads();
    conv_core_256((const char*)X[0], (const char*)X[1], wh, wl, bias,
                  out + (size_t)roi * 49 * CC, 1, t);
}

// ---------------------------------------------------------------------------
// Kernel 5: final conv 256->42 (padded 48).  4 waves split K by tap groups
// {3,2,2,2}; partials reduced through LDS (X reused).  Output (K,42,7,7).
// ---------------------------------------------------------------------------
__global__ __launch_bounds__(256, 2) void conv5_mfma_kernel(
        const float* __restrict__ in, float* __restrict__ out,
        const ushort_t* __restrict__ wh, const ushort_t* __restrict__ wl,
        const float* __restrict__ b5) {
    __shared__ ushort_t X[2][XROWS * 256];
    const int roi = blockIdx.x, t = threadIdx.x;
    stage_roi(in + (size_t)roi * 49 * CC, X[0], X[1], t);
    __syncthreads();

    const int wv = t >> 6, l = t & 63;
    const int lr = l & 15, lk = l >> 4;
    const int lk16 = lk * 16;

    f32x4 acc[4][3];
    #pragma unroll
    for (int a = 0; a < 4; ++a)
        #pragma unroll
        for (int b = 0; b < 3; ++b) acc[a][b] = {0.f, 0.f, 0.f, 0.f};

    const int bvoff = (lr * 256 + lk * 8) * 2;
    const char* Xhc = (const char*)X[0];
    const char* Xlc = (const char*)X[1];
    const int t0 = (wv == 0) ? 0 : (2 * wv + 1);
    const int t1 = 2 * wv + 3;

    for (int tap = t0; tap < t1; ++tap) {
        const int ky = tap / 3 - 1, kx = tap % 3 - 1;
        int arow[4], amask[4];
        #pragma unroll
        for (int mt = 0; mt < 4; ++mt) {
            int m = mt * 16 + lr;
            int py = m / 7, px = m - (m / 7) * 7;
            int y = py + ky, x = px + kx;
            bool ok = (m < 49) && (y >= 0) && (y < 7) && (x >= 0) && (x < 7);
            int srow = ok ? (y * 7 + x) : ZROW;
            arow[mt]  = srow * 512;
            amask[mt] = (srow & 7) << 4;
        }
        const char* wht = (const char*)wh + tap * 24576;   // 48*256*2
        const char* wlt = (const char*)wl + tap * 24576;
        #pragma unroll
        for (int kc = 0; kc < 8; ++kc) {
            short8 ah[4], al[4];
            #pragma unroll
            for (int mt = 0; mt < 4; ++mt) {
                const int off = arow[mt] + ((lk16 + kc * 64) ^ amask[mt]);
                ah[mt] = *(const short8*)(Xhc + off);
                al[mt] = *(const short8*)(Xlc + off);
            }
            #pragma unroll
            for (int nt = 0; nt < 3; ++nt) {
                const int woff = bvoff + nt * 8192 + kc * 64;
                short8 bh = *(const short8*)(wht + woff);
                short8 bl = *(const short8*)(wlt + woff);
                #pragma unroll
                for (int mt = 0; mt < 4; ++mt)
                    acc[mt][nt] = __builtin_amdgcn_mfma_f32_16x16x32_bf16(ah[mt], bh, acc[mt][nt], 0, 0, 0);
                #pragma unroll
                for (int mt = 0; mt < 4; ++mt)
                    acc[mt][nt] = __builtin_amdgcn_mfma_f32_16x16x32_bf16(al[mt], bh, acc[mt][nt], 0, 0, 0);
                #pragma unroll
                for (int mt = 0; mt < 4; ++mt)
                    acc[mt][nt] = __builtin_amdgcn_mfma_f32_16x16x32_bf16(ah[mt], bl, acc[mt][nt], 0, 0, 0);
            }
        }
    }

    __syncthreads();                       // all waves done reading X
    float* P = (float*)X;                  // reuse: [wave][m64][n48] = 48KB
    #pragma unroll
    for (int nt = 0; nt < 3; ++nt)
        #pragma unroll
        for (int mt = 0; mt < 4; ++mt)
            #pragma unroll
            for (int r = 0; r < 4; ++r) {
                int m = mt * 16 + lk * 4 + r;
                P[wv * 3072 + m * 48 + nt * 16 + lr] = acc[mt][nt][r];
            }
    __syncthreads();

    for (int i = t; i < 49 * CO5; i += 256) {     // 2058 outputs
        int n = i / 49, m = i % 49;
        float s = P[m * 48 + n] + P[3072 + m * 48 + n]
                + P[6144 + m * 48 + n] + P[9216 + m * 48 + n] + b5[n];
        out[(size_t)roi * (49 * CO5) + i] = s;    // out[roi][co][py][px]
    }
}

// ---------------------------------------------------------------------------
extern "C" void kernel_launch(void* const* d_in, const int* in_sizes, int n_in,
                              void* d_out, int out_size, void* d_ws, size_t ws_size,
                              hipStream_t stream) {
    const float* features = (const float*)d_in[0];
    const float* rois     = (const float*)d_in[1];
    const float* W1 = (const float*)d_in[2];
    const float* b1 = (const float*)d_in[3];
    const float* W2 = (const float*)d_in[4];
    const float* b2 = (const float*)d_in[5];
    const float* W3 = (const float*)d_in[6];
    const float* b3 = (const float*)d_in[7];
    const float* W4 = (const float*)d_in[8];
    const float* b4 = (const float*)d_in[9];
    const float* W5 = (const float*)d_in[10];
    const float* b5 = (const float*)d_in[11];
    float* out = (float*)d_out;

    const int K = in_sizes[1] / 5;   // 1024 rois

    // workspace layout (bytes)
    char* wsb = (char*)d_ws;
    float* ft   = (float*)wsb;                                // 31,129,600 B
    float* buf0 = (float*)(wsb + 31129600);                   // 51,380,224 B
    char* wb = wsb + 31129600 + 51380224;
    ushort_t* w1h = (ushort_t*)(wb + 0 * 1179648);
    ushort_t* w1l = (ushort_t*)(wb + 1 * 1179648);
    ushort_t* w2h = (ushort_t*)(wb + 2 * 1179648);
    ushort_t* w2l = (ushort_t*)(wb + 3 * 1179648);
    ushort_t* w3h = (ushort_t*)(wb + 4 * 1179648);
    ushort_t* w3l = (ushort_t*)(wb + 5 * 1179648);
    ushort_t* w4h = (ushort_t*)(wb + 6 * 1179648);
    ushort_t* w4l = (ushort_t*)(wb + 7 * 1179648);
    ushort_t* w5h = (ushort_t*)(wb + 8 * 1179648);
    ushort_t* w5l = (ushort_t*)(wb + 8 * 1179648 + 221184);
    // total = 92,389,376 B

    // 1. feature transpose
    {
        dim3 grid((WW + 31) / 32, CC / 32, BB * HH);
        dim3 block(32, 8);
        ftrans_kernel<<<grid, block, 0, stream>>>(features, ft);
    }
    // 2. weight prep (hi/lo bf16, [tap][co][ci])
    wprep_kernel<<<2304, 256, 0, stream>>>(W1, w1h, w1l);
    wprep_kernel<<<2304, 256, 0, stream>>>(W2, w2h, w2l);
    wprep_kernel<<<2304, 256, 0, stream>>>(W3, w3h, w3l);
    wprep_kernel<<<2304, 256, 0, stream>>>(W4, w4h, w4l);
    wprep5_kernel<<<432, 256, 0, stream>>>(W5, w5h, w5l);
    // 3. fused roi-align + conv1 -> buf0
    conv1_fused_kernel<<<K, 256, 0, stream>>>(ft, rois, buf0, w1h, w1l, b1);
    // 4. conv chain on MFMA, in-place on buf0
    conv_mfma_kernel<<<K, 256, 0, stream>>>(buf0, buf0, w2h, w2l, b2);
    conv_mfma_kernel<<<K, 256, 0, stream>>>(buf0, buf0, w3h, w3l, b3);
    conv_mfma_kernel<<<K, 256, 0, stream>>>(buf0, buf0, w4h, w4l, b4);
    // 5. final conv -> out
    conv5_mfma_kernel<<<K, 256, 0, stream>>>(buf0, out, w5h, w5l, b5);
}

// Round 10
// 1297.413 us; speedup vs baseline: 1.6808x; 1.0301x over previous
//
#include <hip/hip_runtime.h>
#include <hip/hip_bf16.h>

// Problem constants: B=2, C=256, H=100, W=152, K=1024 rois, OUT=7, co5=42
#define BB   2
#define CC   256
#define HH   100
#define WW   152
#define CO5  42

// LDS staging geometry: rows 0..48 = data, row 49 = shared zero/pad row.
#define XROWS 50
#define ZROW  49

typedef short short8 __attribute__((ext_vector_type(8)));   // 8 bf16 (4 VGPRs)
typedef float f32x4 __attribute__((ext_vector_type(4)));    // MFMA accumulator

typedef unsigned int uint_t;
typedef unsigned short ushort_t;

__device__ __forceinline__ uint_t bf16_rne(float x) {
    uint_t u = __float_as_uint(x);
    return (u + 0x7fffu + ((u >> 16) & 1u)) >> 16;
}
__device__ __forceinline__ void split_bf16(float x, uint_t& h, uint_t& l) {
    h = bf16_rne(x);
    float hf = __uint_as_float(h << 16);
    l = bf16_rne(x - hf);     // x - hf exact in fp32
}

// ---------------------------------------------------------------------------
// Kernel 1: NCHW -> NHWC feature transpose (for coalesced roi-align gathers)
// ---------------------------------------------------------------------------
__global__ void ftrans_kernel(const float* __restrict__ f, float* __restrict__ ft) {
    __shared__ float tile[32][33];
    const int x0 = blockIdx.x * 32;
    const int c0 = blockIdx.y * 32;
    const int by = blockIdx.z;            // b*H + y
    const int b = by / HH, y = by % HH;
    const int tx = threadIdx.x, ty = threadIdx.y;
    #pragma unroll
    for (int j = 0; j < 4; ++j) {
        int c = c0 + ty + j * 8;
        int x = x0 + tx;
        if (x < WW)
            tile[ty + j * 8][tx] = f[(((size_t)b * CC + c) * HH + y) * WW + x];
    }
    __syncthreads();
    #pragma unroll
    for (int j = 0; j < 4; ++j) {
        int x = x0 + ty + j * 8;
        int c = c0 + tx;
        if (x < WW)
            ft[(((size_t)b * HH + y) * WW + x) * CC + c] = tile[tx][ty + j * 8];
    }
}

// ---------------------------------------------------------------------------
// Kernel 2: weight prep.  W[co][ci][3][3] fp32 -> wh/wl[tap][co][ci] bf16 hi/lo.
// ---------------------------------------------------------------------------
__global__ void wprep_kernel(const float* __restrict__ W,
                             ushort_t* __restrict__ wh, ushort_t* __restrict__ wl) {
    int idx = blockIdx.x * 256 + threadIdx.x;     // 9*256*256 = 589,824 exact
    int tap = idx >> 16;
    int rem = idx & 0xffff;
    int co = rem >> 8, ci = rem & 255;
    float v = W[(size_t)((co << 8) + ci) * 9 + tap];
    uint_t h, l; split_bf16(v, h, l);
    wh[idx] = (ushort_t)h;
    wl[idx] = (ushort_t)l;
}

// Final layer: pad co 42 -> 48.  wh/wl[tap][48][256].
__global__ void wprep5_kernel(const float* __restrict__ W,
                              ushort_t* __restrict__ wh, ushort_t* __restrict__ wl) {
    int idx = blockIdx.x * 256 + threadIdx.x;     // 9*48*256 = 110,592 exact
    int tap = idx / 12288;
    int rem = idx % 12288;
    int co = rem >> 8, ci = rem & 255;
    float v = (co < CO5) ? W[(size_t)((co << 8) + ci) * 9 + tap] : 0.0f;
    uint_t h, l; split_bf16(v, h, l);
    wh[idx] = (ushort_t)h;
    wl[idx] = (ushort_t)l;
}

// ---------------------------------------------------------------------------
// LDS staging from a [49][256] fp32 global tile -> hi/lo bf16 [50][256],
// row 49 zeroed.  XOR swizzle on the full within-row byte offset:
//   addr = row*512 + (byteoff ^ ((row&7)<<4))
// ---------------------------------------------------------------------------
__device__ __forceinline__ void stage_roi(const float* __restrict__ src,
                                          ushort_t* Xh, ushort_t* Xl, int t) {
    const float2* s2 = (const float2*)src;
    const int half = t >> 7;          // 0/1: even/odd rows
    const int cw = t & 127;           // ci pair index
    #pragma unroll
    for (int i = 0; i < 25; ++i) {
        int row = i * 2 + half;       // covers 0..49 exactly
        int addr = row * 512 + ((cw * 4) ^ ((row & 7) << 4));
        uint_t ph = 0u, pl = 0u;
        if (row < 49) {
            float2 v = s2[row * 128 + cw];
            uint_t h0, l0, h1, l1;
            split_bf16(v.x, h0, l0);
            split_bf16(v.y, h1, l1);
            ph = h0 | (h1 << 16);
            pl = l0 | (l1 << 16);
        }
        *(uint_t*)((char*)Xh + addr) = ph;
        *(uint_t*)((char*)Xl + addr) = pl;
    }
}

// ---------------------------------------------------------------------------
// Fused roi-align staging: bilinear-sample NHWC features straight into the
// swizzled LDS hi/lo buffers (skips the global roi-align round trip).
// ---------------------------------------------------------------------------
__device__ __forceinline__ void stage_roi_align(const float* __restrict__ ft,
                                                const float* __restrict__ rois,
                                                ushort_t* Xh, ushort_t* Xl,
                                                int roi, int t) {
    const float bf = rois[roi * 5 + 0];
    const float x1 = rois[roi * 5 + 1];
    const float y1 = rois[roi * 5 + 2];
    const float x2 = rois[roi * 5 + 3];
    const float y2 = rois[roi * 5 + 4];
    const int b = (int)bf;
    const float rw = fmaxf(x2 - x1, 1.0f);
    const float rh = fmaxf(y2 - y1, 1.0f);
    const float stepy = rh / 7.0f;
    const float stepx = rw / 7.0f;

    const int half = t >> 7;
    const int cw = t & 127;
    const float* base = ft + (size_t)b * HH * WW * CC + cw * 2;

    #pragma unroll
    for (int i = 0; i < 25; ++i) {
        int row = i * 2 + half;       // 0..49
        int addr = row * 512 + ((cw * 4) ^ ((row & 7) << 4));
        uint_t ph = 0u, pl = 0u;
        if (row < 49) {
            int py = row / 7, px = row - (row / 7) * 7;
            float sx = 0.0f, sy_ = 0.0f;    // accum for ci pair (.x, .y)
            #pragma unroll
            for (int j = 0; j < 4; ++j) {
                const int syi = py * 2 + (j >> 1);
                const int sxi = px * 2 + (j & 1);
                float gy = y1 + ((float)syi + 0.5f) * 0.5f * stepy;
                float gx = x1 + ((float)sxi + 0.5f) * 0.5f * stepx;
                float yc = fminf(fmaxf(gy, 0.0f), (float)(HH - 1));
                float xc = fminf(fmaxf(gx, 0.0f), (float)(WW - 1));
                float y0f = fminf(floorf(yc), (float)(HH - 2));
                float x0f = fminf(floorf(xc), (float)(WW - 2));
                float wy = yc - y0f;
                float wx = xc - x0f;
                int y0 = (int)y0f, x0 = (int)x0f;
                const float* p = base + ((size_t)y0 * WW + x0) * CC;
                float2 v00 = *(const float2*)(p);
                float2 v01 = *(const float2*)(p + CC);
                float2 v10 = *(const float2*)(p + (size_t)WW * CC);
                float2 v11 = *(const float2*)(p + (size_t)WW * CC + CC);
                float w00 = (1.0f - wy) * (1.0f - wx);
                float w01 = (1.0f - wy) * wx;
                float w10 = wy * (1.0f - wx);
                float w11 = wy * wx;
                sx  += w00 * v00.x + w01 * v01.x + w10 * v10.x + w11 * v11.x;
                sy_ += w00 * v00.y + w01 * v01.y + w10 * v10.y + w11 * v11.y;
            }
            uint_t h0, l0, h1, l1;
            split_bf16(0.25f * sx, h0, l0);
            split_bf16(0.25f * sy_, h1, l1);
            ph = h0 | (h1 << 16);
            pl = l0 | (l1 << 16);
        }
        *(uint_t*)((char*)Xh + addr) = ph;
        *(uint_t*)((char*)Xl + addr) = pl;
    }
}

// ---------------------------------------------------------------------------
// Shared MFMA conv core (256->256): flattened (tap,kc) -> 72 iterations with
// a SOFTWARE-PIPELINED B-operand: two named register sets (bhA/blA, bhB/blB)
// alternate; iteration it issues the 8 global loads for it+1 BEFORE the 48
// MFMAs of it.  No barrier in this loop -> compiler can emit counted vmcnt
// (T4 pattern) instead of a drain.  R8 diagnosis: 188 unified regs/wave caps
// us at 2 waves/SIMD, so latency must be hidden IN-WAVE, not by occupancy.
// ---------------------------------------------------------------------------
__device__ __forceinline__ void conv_core_256(
        const char* Xhc, const char* Xlc,
        const ushort_t* __restrict__ wh, const ushort_t* __restrict__ wl,
        const float* __restrict__ bias, float* __restrict__ outp,
        int relu, int t) {
    const int wv = t >> 6, l = t & 63;
    const int lr = l & 15;               // A-row-in-tile / B-col / D-col
    const int lk = l >> 4;               // k-group
    const int n0 = wv * 64;
    const int lk16 = lk * 16;

    f32x4 acc[4][4];
    #pragma unroll
    for (int a = 0; a < 4; ++a)
        #pragma unroll
        for (int b = 0; b < 4; ++b) acc[a][b] = {0.f, 0.f, 0.f, 0.f};

    const int bvoff = ((n0 + lr) * 256 + lk * 8) * 2;   // byte off within tap

    int arow[4], amask[4];               // A-row remap for the CURRENT tap

#define COMPUTE_A(tap_) {                                                   \
    const int ky_ = (tap_) / 3 - 1, kx_ = (tap_) % 3 - 1;                   \
    _Pragma("unroll")                                                       \
    for (int mt = 0; mt < 4; ++mt) {                                        \
        int m_ = mt * 16 + lr;                                              \
        int py_ = m_ / 7, px_ = m_ - (m_ / 7) * 7;                          \
        int y_ = py_ + ky_, x_ = px_ + kx_;                                 \
        bool ok_ = (m_ < 49) && (y_ >= 0) && (y_ < 7) && (x_ >= 0) && (x_ < 7); \
        int srow_ = ok_ ? (y_ * 7 + x_) : ZROW;                             \
        arow[mt]  = srow_ * 512;                                            \
        amask[mt] = (srow_ & 7) << 4;                                       \
    } }

#define LOAD_B(bh_, bl_, it_) {                                             \
    const char* wht_ = (const char*)wh + ((it_) >> 3) * 131072;             \
    const char* wlt_ = (const char*)wl + ((it_) >> 3) * 131072;             \
    const int ko_ = ((it_) & 7) * 64 + bvoff;                               \
    _Pragma("unroll")                                                       \
    for (int nt = 0; nt < 4; ++nt) {                                        \
        bh_[nt] = *(const short8*)(wht_ + nt * 8192 + ko_);                 \
        bl_[nt] = *(const short8*)(wlt_ + nt * 8192 + ko_);                 \
    } }

#define MFMA_BLOCK(bh_, bl_, kc_) {                                         \
    short8 ah_[4], al_[4];                                                  \
    _Pragma("unroll")                                                       \
    for (int mt = 0; mt < 4; ++mt) {                                        \
        const int off_ = arow[mt] + ((lk16 + (kc_) * 64) ^ amask[mt]);      \
        ah_[mt] = *(const short8*)(Xhc + off_);                             \
        al_[mt] = *(const short8*)(Xlc + off_);                             \
    }                                                                       \
    _Pragma("unroll")                                                       \
    for (int nt = 0; nt < 4; ++nt) {                                        \
        _Pragma("unroll")                                                   \
        for (int mt = 0; mt < 4; ++mt)                                      \
            acc[mt][nt] = __builtin_amdgcn_mfma_f32_16x16x32_bf16(ah_[mt], bh_[nt], acc[mt][nt], 0, 0, 0); \
        _Pragma("unroll")                                                   \
        for (int mt = 0; mt < 4; ++mt)                                      \
            acc[mt][nt] = __builtin_amdgcn_mfma_f32_16x16x32_bf16(al_[mt], bh_[nt], acc[mt][nt], 0, 0, 0); \
        _Pragma("unroll")                                                   \
        for (int mt = 0; mt < 4; ++mt)                                      \
            acc[mt][nt] = __builtin_amdgcn_mfma_f32_16x16x32_bf16(ah_[mt], bl_[nt], acc[mt][nt], 0, 0, 0); \
    } }

    short8 bhA[4], blA[4], bhB[4], blB[4];
    COMPUTE_A(0);
    LOAD_B(bhA, blA, 0);

    // 72 flat iterations (9 taps x 8 kc), manually unrolled by 2 so each
    // register set has a static name (rule: no runtime-indexed reg arrays).
    // Tap boundaries (it % 8 == 0) always land in the even slot.
    for (int it = 0; it < 72; it += 2) {
        LOAD_B(bhB, blB, it + 1);                  // prefetch next (it+1<=71)
        if ((it & 7) == 0 && it) COMPUTE_A(it >> 3);
        MFMA_BLOCK(bhA, blA, it & 7);
        if (it + 2 < 72) LOAD_B(bhA, blA, it + 2); // prefetch next-next
        MFMA_BLOCK(bhB, blB, (it + 1) & 7);
    }

#undef COMPUTE_A
#undef LOAD_B
#undef MFMA_BLOCK

    #pragma unroll
    for (int nt = 0; nt < 4; ++nt) {
        const int co = n0 + nt * 16 + lr;
        const float bv = bias[co];
        #pragma unroll
        for (int mt = 0; mt < 4; ++mt) {
            #pragma unroll
            for (int r = 0; r < 4; ++r) {
                int m = mt * 16 + lk * 4 + r;         // D row = (l>>4)*4+reg
                if (m < 49) {
                    float v = acc[mt][nt][r] + bv;
                    if (relu) v = fmaxf(v, 0.0f);
                    outp[m * 256 + co] = v;           // D col = l&15 -> co
                }
            }
        }
    }
}

// ---------------------------------------------------------------------------
// Kernel 3: fused roi-align + conv1 (256->256, relu)
// __launch_bounds__(256, 2): min-waves=3 caused a spill catastrophe (r7).
// ---------------------------------------------------------------------------
__global__ __launch_bounds__(256, 2) void conv1_fused_kernel(
        const float* __restrict__ ft, const float* __restrict__ rois,
        float* __restrict__ out,
        const ushort_t* __restrict__ wh, const ushort_t* __restrict__ wl,
        const float* __restrict__ bias) {
    __shared__ ushort_t X[2][XROWS * 256];   // 51,200 B
    const int roi = blockIdx.x, t = threadIdx.x;
    stage_roi_align(ft, rois, X[0], X[1], roi, t);
    __syncthreads();
    conv_core_256((const char*)X[0], (const char*)X[1], wh, wl, bias,
                  out + (size_t)roi * 49 * CC, 1, t);
}

// ---------------------------------------------------------------------------
// Kernel 4: mid conv (256->256, relu), in-place safe.
// ---------------------------------------------------------------------------
__global__ __launch_bounds__(256, 2) void conv_mfma_kernel(
        const float* __restrict__ in, float* __restrict__ out,
        const ushort_t* __restrict__ wh, const ushort_t* __restrict__ wl,
        const float* __restrict__ bias) {
    __shared__ ushort_t X[2][XROWS * 256];
    const int roi = blockIdx.x, t = threadIdx.x;
    stage_roi(in + (size_t)roi * 49 * CC, X[0], X[1], t);
    __syncthreads();
    conv_core_256((const char*)X[0], (const char*)X[1], wh, wl, bias,
                  out + (size_t)roi * 49 * CC, 1, t);
}

// ---------------------------------------------------------------------------
// Kernel 5: final conv 256->42 (padded 48).  4 waves split K by tap groups
// {3,2,2,2}; partials reduced through LDS (X reused).  Output (K,42,7,7).
// (Left unpipelined this round — small fraction of total; single-variable
//  discipline on the pipeline experiment.)
// ---------------------------------------------------------------------------
__global__ __launch_bounds__(256, 2) void conv5_mfma_kernel(
        const float* __restrict__ in, float* __restrict__ out,
        const ushort_t* __restrict__ wh, const ushort_t* __restrict__ wl,
        const float* __restrict__ b5) {
    __shared__ ushort_t X[2][XROWS * 256];
    const int roi = blockIdx.x, t = threadIdx.x;
    stage_roi(in + (size_t)roi * 49 * CC, X[0], X[1], t);
    __syncthreads();

    const int wv = t >> 6, l = t & 63;
    const int lr = l & 15, lk = l >> 4;
    const int lk16 = lk * 16;

    f32x4 acc[4][3];
    #pragma unroll
    for (int a = 0; a < 4; ++a)
        #pragma unroll
        for (int b = 0; b < 3; ++b) acc[a][b] = {0.f, 0.f, 0.f, 0.f};

    const int bvoff = (lr * 256 + lk * 8) * 2;
    const char* Xhc = (const char*)X[0];
    const char* Xlc = (const char*)X[1];
    const int t0 = (wv == 0) ? 0 : (2 * wv + 1);
    const int t1 = 2 * wv + 3;

    for (int tap = t0; tap < t1; ++tap) {
        const int ky = tap / 3 - 1, kx = tap % 3 - 1;
        int arow[4], amask[4];
        #pragma unroll
        for (int mt = 0; mt < 4; ++mt) {
            int m = mt * 16 + lr;
            int py = m / 7, px = m - (m / 7) * 7;
            int y = py + ky, x = px + kx;
            bool ok = (m < 49) && (y >= 0) && (y < 7) && (x >= 0) && (x < 7);
            int srow = ok ? (y * 7 + x) : ZROW;
            arow[mt]  = srow * 512;
            amask[mt] = (srow & 7) << 4;
        }
        const char* wht = (const char*)wh + tap * 24576;   // 48*256*2
        const char* wlt = (const char*)wl + tap * 24576;
        #pragma unroll
        for (int kc = 0; kc < 8; ++kc) {
            short8 ah[4], al[4];
            #pragma unroll
            for (int mt = 0; mt < 4; ++mt) {
                const int off = arow[mt] + ((lk16 + kc * 64) ^ amask[mt]);
                ah[mt] = *(const short8*)(Xhc + off);
                al[mt] = *(const short8*)(Xlc + off);
            }
            #pragma unroll
            for (int nt = 0; nt < 3; ++nt) {
                const int woff = bvoff + nt * 8192 + kc * 64;
                short8 bh = *(const short8*)(wht + woff);
                short8 bl = *(const short8*)(wlt + woff);
                #pragma unroll
                for (int mt = 0; mt < 4; ++mt)
                    acc[mt][nt] = __builtin_amdgcn_mfma_f32_16x16x32_bf16(ah[mt], bh, acc[mt][nt], 0, 0, 0);
                #pragma unroll
                for (int mt = 0; mt < 4; ++mt)
                    acc[mt][nt] = __builtin_amdgcn_mfma_f32_16x16x32_bf16(al[mt], bh, acc[mt][nt], 0, 0, 0);
                #pragma unroll
                for (int mt = 0; mt < 4; ++mt)
                    acc[mt][nt] = __builtin_amdgcn_mfma_f32_16x16x32_bf16(ah[mt], bl, acc[mt][nt], 0, 0, 0);
            }
        }
    }

    __syncthreads();                       // all waves done reading X
    float* P = (float*)X;                  // reuse: [wave][m64][n48] = 48KB
    #pragma unroll
    for (int nt = 0; nt < 3; ++nt)
        #pragma unroll
        for (int mt = 0; mt < 4; ++mt)
            #pragma unroll
            for (int r = 0; r < 4; ++r) {
                int m = mt * 16 + lk * 4 + r;
                P[wv * 3072 + m * 48 + nt * 16 + lr] = acc[mt][nt][r];
            }
    __syncthreads();

    for (int i = t; i < 49 * CO5; i += 256) {     // 2058 outputs
        int n = i / 49, m = i % 49;
        float s = P[m * 48 + n] + P[3072 + m * 48 + n]
                + P[6144 + m * 48 + n] + P[9216 + m * 48 + n] + b5[n];
        out[(size_t)roi * (49 * CO5) + i] = s;    // out[roi][co][py][px]
    }
}

// ---------------------------------------------------------------------------
extern "C" void kernel_launch(void* const* d_in, const int* in_sizes, int n_in,
                              void* d_out, int out_size, void* d_ws, size_t ws_size,
                              hipStream_t stream) {
    const float* features = (const float*)d_in[0];
    const float* rois     = (const float*)d_in[1];
    const float* W1 = (const float*)d_in[2];
    const float* b1 = (const float*)d_in[3];
    const float* W2 = (const float*)d_in[4];
    const float* b2 = (const float*)d_in[5];
    const float* W3 = (const float*)d_in[6];
    const float* b3 = (const float*)d_in[7];
    const float* W4 = (const float*)d_in[8];
    const float* b4 = (const float*)d_in[9];
    const float* W5 = (const float*)d_in[10];
    const float* b5 = (const float*)d_in[11];
    float* out = (float*)d_out;

    const int K = in_sizes[1] / 5;   // 1024 rois

    // workspace layout (bytes)
    char* wsb = (char*)d_ws;
    float* ft   = (float*)wsb;                                // 31,129,600 B
    float* buf0 = (float*)(wsb + 31129600);                   // 51,380,224 B
    char* wb = wsb + 31129600 + 51380224;
    ushort_t* w1h = (ushort_t*)(wb + 0 * 1179648);
    ushort_t* w1l = (ushort_t*)(wb + 1 * 1179648);
    ushort_t* w2h = (ushort_t*)(wb + 2 * 1179648);
    ushort_t* w2l = (ushort_t*)(wb + 3 * 1179648);
    ushort_t* w3h = (ushort_t*)(wb + 4 * 1179648);
    ushort_t* w3l = (ushort_t*)(wb + 5 * 1179648);
    ushort_t* w4h = (ushort_t*)(wb + 6 * 1179648);
    ushort_t* w4l = (ushort_t*)(wb + 7 * 1179648);
    ushort_t* w5h = (ushort_t*)(wb + 8 * 1179648);
    ushort_t* w5l = (ushort_t*)(wb + 8 * 1179648 + 221184);
    // total = 92,389,376 B

    // 1. feature transpose
    {
        dim3 grid((WW + 31) / 32, CC / 32, BB * HH);
        dim3 block(32, 8);
        ftrans_kernel<<<grid, block, 0, stream>>>(features, ft);
    }
    // 2. weight prep (hi/lo bf16, [tap][co][ci])
    wprep_kernel<<<2304, 256, 0, stream>>>(W1, w1h, w1l);
    wprep_kernel<<<2304, 256, 0, stream>>>(W2, w2h, w2l);
    wprep_kernel<<<2304, 256, 0, stream>>>(W3, w3h, w3l);
    wprep_kernel<<<2304, 256, 0, stream>>>(W4, w4h, w4l);
    wprep5_kernel<<<432, 256, 0, stream>>>(W5, w5h, w5l);
    // 3. fused roi-align + conv1 -> buf0
    conv1_fused_kernel<<<K, 256, 0, stream>>>(ft, rois, buf0, w1h, w1l, b1);
    // 4. conv chain on MFMA, in-place on buf0
    conv_mfma_kernel<<<K, 256, 0, stream>>>(buf0, buf0, w2h, w2l, b2);
    conv_mfma_kernel<<<K, 256, 0, stream>>>(buf0, buf0, w3h, w3l, b3);
    conv_mfma_kernel<<<K, 256, 0, stream>>>(buf0, buf0, w4h, w4l, b4);
    // 5. final conv -> out
    conv5_mfma_kernel<<<K, 256, 0, stream>>>(buf0, out, w5h, w5l, b5);
}